// Round 3
// baseline (347.654 us; speedup 1.0000x reference)
//
#include <hip/hip_runtime.h>
#include <math.h>

#define N 512
#define C 16
#define LT 3
#define AGG_IN 1028   // N + (NLAYERS + N), NLAYERS=4

// Branchless tanh: tanh(x) = sign(x) * (1 - t)/(1 + t), t = exp(-2|x|).
__device__ __forceinline__ float fast_tanh(float x) {
    float ax = fabsf(x);
    float t  = __expf(-2.0f * ax);
    float r  = __fdividef(1.0f - t, 1.0f + t);
    return copysignf(r, x);
}

__global__ __launch_bounds__(512) void zero_partials(float* __restrict__ part, int n) {
    int i = blockIdx.x * blockDim.x + threadIdx.x;
    if (i < n) part[i] = 0.f;
}

// Edge kernel for layer l. Block = (p-chunk pc, q), 256 threads.
// Thread t: edge e = t/4 within chunk (p = pc*64 + e), channel-quad j = t%4.
// All big loads are lane-contiguous float4s (coalesced).
__global__ __launch_bounds__(256) void edge_kernel(
    const float* __restrict__ a_in,    // [N]
    const float* __restrict__ vec_W,   // [LT,N,N,C]
    const float* __restrict__ vec_b,   // [LT,N,N,C]
    const float* __restrict__ syn_W1,  // [LT,N,N,3,C]
    const float* __restrict__ syn_b1,  // [LT,N,N,3]
    const float* __restrict__ syn_W2,  // [LT,N,N,3]
    const float* __restrict__ syn_b2,  // [LT,N,N]
    const float* __restrict__ agg_W1,  // [LT,N,3,AGG_IN]
    float* __restrict__ part,          // [N*3] partials for this layer
    int l)
{
    const int q  = blockIdx.y;
    const int pc = blockIdx.x;          // 0..7
    const int t  = threadIdx.x;         // 0..255
    const int e  = t >> 2;              // 0..63
    const int j  = t & 3;               // channel quad
    const int p  = pc * 64 + e;

    const size_t edge = ((size_t)(l * N + q)) * N + p;

    const float av = a_in[p];

    // vec: lane-contiguous float4 (16B/lane, fully coalesced)
    const float4 w = ((const float4*)(vec_W + edge * C))[j];
    const float4 b = ((const float4*)(vec_b + edge * C))[j];

    float4 f;
    f.x = fast_tanh(fmaf(av, w.x, b.x));
    f.y = fast_tanh(fmaf(av, w.y, b.y));
    f.z = fast_tanh(fmaf(av, w.z, b.z));
    f.w = fast_tanh(fmaf(av, w.w, b.w));

    // syn_W1: per o, lane loads its quad's float4 (64B contiguous per edge)
    const float4* sW1 = (const float4*)(syn_W1 + edge * 48);
    float d0, d1, d2;
    {
        float4 wv = sW1[0 * 4 + j];
        d0 = fmaf(wv.x, f.x, fmaf(wv.y, f.y, fmaf(wv.z, f.z, wv.w * f.w)));
        wv = sW1[1 * 4 + j];
        d1 = fmaf(wv.x, f.x, fmaf(wv.y, f.y, fmaf(wv.z, f.z, wv.w * f.w)));
        wv = sW1[2 * 4 + j];
        d2 = fmaf(wv.x, f.x, fmaf(wv.y, f.y, fmaf(wv.z, f.z, wv.w * f.w)));
    }
    // combine the 4 channel-quads of this edge (quad = lanes e*4 .. e*4+3)
    d0 += __shfl_xor(d0, 1, 64);  d0 += __shfl_xor(d0, 2, 64);
    d1 += __shfl_xor(d1, 1, 64);  d1 += __shfl_xor(d1, 2, 64);
    d2 += __shfl_xor(d2, 1, 64);  d2 += __shfl_xor(d2, 2, 64);

    // per-edge scalars (4 lanes redundant -> broadcast from same line)
    float h0 = fast_tanh(d0 + syn_b1[edge * 3 + 0]);
    float h1 = fast_tanh(d1 + syn_b1[edge * 3 + 1]);
    float h2 = fast_tanh(d2 + syn_b1[edge * 3 + 2]);
    float s = syn_b2[edge];
    s = fmaf(syn_W2[edge * 3 + 0], h0, s);
    s = fmaf(syn_W2[edge * 3 + 1], h1, s);
    s = fmaf(syn_W2[edge * 3 + 2], h2, s);
    s = fast_tanh(s);

    // aggregator partial: lane j<3 handles output k=j for its edge
    float pv = 0.f;
    if (j < 3) {
        pv = s * agg_W1[(((size_t)(l * N + q)) * 3 + j) * AGG_IN + p];
    }
    // sum over the 16 edges of this wave (same j lanes)
    pv += __shfl_xor(pv, 4, 64);
    pv += __shfl_xor(pv, 8, 64);
    pv += __shfl_xor(pv, 16, 64);
    pv += __shfl_xor(pv, 32, 64);

    __shared__ float red[3][4];
    const int wave = t >> 6;
    const int lane = t & 63;
    if (lane < 3) red[lane][wave] = pv;   // lane 0,1,2 == j=0,1,2 of edge 0
    __syncthreads();
    if (t < 3) {
        float acc = red[t][0] + red[t][1] + red[t][2] + red[t][3];
        atomicAdd(&part[q * 3 + t], acc);
    }
}

// Per-layer epilogue: one block, thread q finishes node q.
__global__ __launch_bounds__(512) void agg_epilogue(
    const float* __restrict__ part,     // [N*3]
    const float* __restrict__ agg_W1,   // [LT,N,3,AGG_IN]
    const float* __restrict__ agg_b1,   // [LT,N,3]
    const float* __restrict__ agg_W2,   // [LT,N,3]
    const float* __restrict__ agg_b2,   // [LT,N]
    float* __restrict__ a_out,
    int l, int reverse_out)
{
    const int q = threadIdx.x;
    const float* aW1 = agg_W1 + ((size_t)(l * N + q)) * 3 * AGG_IN;
    float h[3];
    #pragma unroll
    for (int k = 0; k < 3; ++k) {
        float acc = part[q * 3 + k];
        acc += aW1[k * AGG_IN + N + (l + 1)];   // layer one-hot column
        acc += aW1[k * AGG_IN + N + 4 + q];     // node one-hot column
        acc += agg_b1[((size_t)(l * N + q)) * 3 + k];
        h[k] = fast_tanh(acc);
    }
    const float* aW2 = agg_W2 + ((size_t)(l * N + q)) * 3;
    float out = agg_b2[l * N + q];
    out = fmaf(aW2[0], h[0], out);
    out = fmaf(aW2[1], h[1], out);
    out = fmaf(aW2[2], h[2], out);
    if (reverse_out) a_out[N - 1 - q] = out;
    else             a_out[q] = out;
}

extern "C" void kernel_launch(void* const* d_in, const int* in_sizes, int n_in,
                              void* d_out, int out_size, void* d_ws, size_t ws_size,
                              hipStream_t stream) {
    const float* x      = (const float*)d_in[0];
    const float* vec_W  = (const float*)d_in[1];
    const float* vec_b  = (const float*)d_in[2];
    const float* syn_W1 = (const float*)d_in[3];
    const float* syn_b1 = (const float*)d_in[4];
    const float* syn_W2 = (const float*)d_in[5];
    const float* syn_b2 = (const float*)d_in[6];
    const float* agg_W1 = (const float*)d_in[7];
    const float* agg_b1 = (const float*)d_in[8];
    const float* agg_W2 = (const float*)d_in[9];
    const float* agg_b2 = (const float*)d_in[10];
    float* out = (float*)d_out;

    float* part = (float*)d_ws;          // [LT][N*3] partial agg dots
    float* a0   = part + LT * N * 3;     // [N]
    float* a1   = a0 + N;                // [N]

    // zero all layers' partial buffers (ws is poisoned before every launch)
    zero_partials<<<(LT * N * 3 + 511) / 512, 512, 0, stream>>>(part, LT * N * 3);

    const dim3 egrid(8, N);

    edge_kernel<<<egrid, 256, 0, stream>>>(x, vec_W, vec_b, syn_W1, syn_b1,
                                           syn_W2, syn_b2, agg_W1,
                                           part + 0 * N * 3, 0);
    agg_epilogue<<<1, N, 0, stream>>>(part + 0 * N * 3, agg_W1, agg_b1, agg_W2,
                                      agg_b2, a0, 0, 0);

    edge_kernel<<<egrid, 256, 0, stream>>>(a0, vec_W, vec_b, syn_W1, syn_b1,
                                           syn_W2, syn_b2, agg_W1,
                                           part + 1 * N * 3, 1);
    agg_epilogue<<<1, N, 0, stream>>>(part + 1 * N * 3, agg_W1, agg_b1, agg_W2,
                                      agg_b2, a1, 1, 0);

    edge_kernel<<<egrid, 256, 0, stream>>>(a1, vec_W, vec_b, syn_W1, syn_b1,
                                           syn_W2, syn_b2, agg_W1,
                                           part + 2 * N * 3, 2);
    agg_epilogue<<<1, N, 0, stream>>>(part + 2 * N * 3, agg_W1, agg_b1, agg_W2,
                                      agg_b2, out, 2, 1);
}

// Round 5
// 308.684 us; speedup vs baseline: 1.1262x; 1.1262x over previous
//
#include <hip/hip_runtime.h>
#include <math.h>

#define N 512
#define C 16
#define AGG_IN 1028   // N + (NLAYERS + N), NLAYERS=4

typedef float v4f __attribute__((ext_vector_type(4)));

// Branchless tanh: tanh(x) = sign(x) * (1 - t)/(1 + t), t = exp(-2|x|).
// rel err ~1e-6, far under the 1.98e-2 threshold.
__device__ __forceinline__ float fast_tanh(float x) {
    float ax = fabsf(x);
    float t  = __expf(-2.0f * ax);
    float r  = __fdividef(1.0f - t, 1.0f + t);
    return copysignf(r, x);
}

__device__ __forceinline__ v4f ntload4(const float* p) {
    return __builtin_nontemporal_load((const v4f*)p);
}

// One layer transition, one block per q (512 threads).
// Thread t: channel-quad j = t&3 of edge e = t>>2; 4 passes cover p = 0..511.
// All 96 MB/layer of fat weights stream through lane-contiguous non-temporal
// float4 loads; per-q aggregation is wave-shuffle + LDS; thread 0 finishes.
__global__ __launch_bounds__(512, 4) void dan_layer_kernel(
    const float* __restrict__ a_in,    // [N]
    float*       __restrict__ a_out,   // [N]
    const float* __restrict__ vec_W,   // [LT,N,N,C]
    const float* __restrict__ vec_b,   // [LT,N,N,C]
    const float* __restrict__ syn_W1,  // [LT,N,N,3,C]
    const float* __restrict__ syn_b1,  // [LT,N,N,3]
    const float* __restrict__ syn_W2,  // [LT,N,N,3]
    const float* __restrict__ syn_b2,  // [LT,N,N]
    const float* __restrict__ agg_W1,  // [LT,N,3,AGG_IN]
    const float* __restrict__ agg_b1,  // [LT,N,3]
    const float* __restrict__ agg_W2,  // [LT,N,3]
    const float* __restrict__ agg_b2,  // [LT,N]
    int l, int reverse_out)
{
    const int q = blockIdx.x;
    const int t = threadIdx.x;
    const int j = t & 3;        // channel quad
    const int e = t >> 2;       // 0..127 edge slot within pass

    __shared__ float red[3][8];
    __shared__ float hsh[3];

    const size_t qbase = ((size_t)(l * N + q)) * N;   // edge base for p=0
    const int jc = (j < 3) ? j : 2;                    // clamped for aW1 addr
    const float* aW1q = agg_W1 + ((size_t)(l * N + q)) * 3 * AGG_IN + (size_t)jc * AGG_IN;

    float pv = 0.f;   // partial of dot(s[q,:], aW1[k=j,:N]) for j<3

    for (int pass = 0; pass < 4; ++pass) {
        const int p = pass * 128 + e;
        const size_t edge = qbase + p;

        const float av = a_in[p];

        // fat streams: lane-contiguous 16B non-temporal loads
        const v4f w  = ntload4(vec_W  + edge * C  + j * 4);
        const v4f b  = ntload4(vec_b  + edge * C  + j * 4);
        const v4f s0 = ntload4(syn_W1 + edge * 48 + 0 * C + j * 4);
        const v4f s1 = ntload4(syn_W1 + edge * 48 + 1 * C + j * 4);
        const v4f s2 = ntload4(syn_W1 + edge * 48 + 2 * C + j * 4);

        float f0 = fast_tanh(fmaf(av, w.x, b.x));
        float f1 = fast_tanh(fmaf(av, w.y, b.y));
        float f2 = fast_tanh(fmaf(av, w.z, b.z));
        float f3 = fast_tanh(fmaf(av, w.w, b.w));

        float d0 = fmaf(s0.x, f0, fmaf(s0.y, f1, fmaf(s0.z, f2, s0.w * f3)));
        float d1 = fmaf(s1.x, f0, fmaf(s1.y, f1, fmaf(s1.z, f2, s1.w * f3)));
        float d2 = fmaf(s2.x, f0, fmaf(s2.y, f1, fmaf(s2.z, f2, s2.w * f3)));

        // combine the 4 channel-quads of this edge (quad = 4 adjacent lanes)
        d0 += __shfl_xor(d0, 1, 64);  d0 += __shfl_xor(d0, 2, 64);
        d1 += __shfl_xor(d1, 1, 64);  d1 += __shfl_xor(d1, 2, 64);
        d2 += __shfl_xor(d2, 1, 64);  d2 += __shfl_xor(d2, 2, 64);

        // per-edge scalars (broadcast within the quad, lines shared across edges)
        float h0 = fast_tanh(d0 + syn_b1[edge * 3 + 0]);
        float h1 = fast_tanh(d1 + syn_b1[edge * 3 + 1]);
        float h2 = fast_tanh(d2 + syn_b1[edge * 3 + 2]);
        float s = syn_b2[edge];
        s = fmaf(syn_W2[edge * 3 + 0], h0, s);
        s = fmaf(syn_W2[edge * 3 + 1], h1, s);
        s = fmaf(syn_W2[edge * 3 + 2], h2, s);
        s = fast_tanh(s);

        // aggregator partial: lane j<3 accumulates output k=j for this edge
        if (j < 3) pv = fmaf(s, aW1q[p], pv);
    }

    // sum over the 16 edges of this wave (lanes with equal j)
    pv += __shfl_xor(pv, 4, 64);
    pv += __shfl_xor(pv, 8, 64);
    pv += __shfl_xor(pv, 16, 64);
    pv += __shfl_xor(pv, 32, 64);

    const int wave = t >> 6;
    const int lane = t & 63;
    if (lane < 3) red[lane][wave] = pv;   // lanes 0..2 hold j=0..2 sums
    __syncthreads();

    if (t < 3) {
        const int k = t;
        float acc = 0.f;
        #pragma unroll
        for (int w = 0; w < 8; ++w) acc += red[k][w];
        const float* aW1 = agg_W1 + ((size_t)(l * N + q)) * 3 * AGG_IN + (size_t)k * AGG_IN;
        acc += aW1[N + (l + 1)];          // layer one-hot column
        acc += aW1[N + 4 + q];            // node one-hot column
        acc += agg_b1[((size_t)(l * N + q)) * 3 + k];
        hsh[k] = fast_tanh(acc);
    }
    __syncthreads();

    if (t == 0) {
        const float* aW2 = agg_W2 + ((size_t)(l * N + q)) * 3;
        float out = agg_b2[l * N + q];
        out = fmaf(aW2[0], hsh[0], out);
        out = fmaf(aW2[1], hsh[1], out);
        out = fmaf(aW2[2], hsh[2], out);
        if (reverse_out) a_out[N - 1 - q] = out;
        else             a_out[q] = out;
    }
}

extern "C" void kernel_launch(void* const* d_in, const int* in_sizes, int n_in,
                              void* d_out, int out_size, void* d_ws, size_t ws_size,
                              hipStream_t stream) {
    const float* x      = (const float*)d_in[0];
    const float* vec_W  = (const float*)d_in[1];
    const float* vec_b  = (const float*)d_in[2];
    const float* syn_W1 = (const float*)d_in[3];
    const float* syn_b1 = (const float*)d_in[4];
    const float* syn_W2 = (const float*)d_in[5];
    const float* syn_b2 = (const float*)d_in[6];
    const float* agg_W1 = (const float*)d_in[7];
    const float* agg_b1 = (const float*)d_in[8];
    const float* agg_W2 = (const float*)d_in[9];
    const float* agg_b2 = (const float*)d_in[10];
    float* out = (float*)d_out;

    float* a0 = (float*)d_ws;        // [N]
    float* a1 = a0 + N;              // [N]

    dan_layer_kernel<<<N, 512, 0, stream>>>(x,  a0,  vec_W, vec_b, syn_W1, syn_b1,
                                            syn_W2, syn_b2, agg_W1, agg_b1, agg_W2, agg_b2,
                                            0, 0);
    dan_layer_kernel<<<N, 512, 0, stream>>>(a0, a1,  vec_W, vec_b, syn_W1, syn_b1,
                                            syn_W2, syn_b2, agg_W1, agg_b1, agg_W2, agg_b2,
                                            1, 0);
    dan_layer_kernel<<<N, 512, 0, stream>>>(a1, out, vec_W, vec_b, syn_W1, syn_b1,
                                            syn_W2, syn_b2, agg_W1, agg_b1, agg_W2, agg_b2,
                                            2, 1);
}